// Round 2
// baseline (280.612 us; speedup 1.0000x reference)
//
#include <hip/hip_runtime.h>

#define T_TOK 1024
#define H_DIM 1024
#define I_DIM 4096
#define NE 8

typedef __attribute__((ext_vector_type(8))) short bf16x8;
typedef __attribute__((ext_vector_type(4))) float f32x4;
typedef __attribute__((ext_vector_type(8))) unsigned short us8;
typedef __attribute__((ext_vector_type(4))) short s16x4;

__device__ __forceinline__ unsigned short f2bf(float x) {
  union { float f; unsigned u; } v; v.f = x;
  unsigned r = v.u + 0x7fffu + ((v.u >> 16) & 1u);  // RNE
  return (unsigned short)(r >> 16);
}

// ---------------- routing: softmax top-2 + renormalize ----------------
__global__ void k_route(const float* __restrict__ gates, int* __restrict__ counts,
                        int* __restrict__ tok_idx, float* __restrict__ tok_w,
                        int* __restrict__ tok_cpy) {
  int t = blockIdx.x * blockDim.x + threadIdx.x;
  if (t >= T_TOK) return;
  float g[NE];
#pragma unroll
  for (int e = 0; e < NE; ++e) g[e] = gates[t * NE + e];
  int i1 = 0; float g1 = g[0];
#pragma unroll
  for (int e = 1; e < NE; ++e) if (g[e] > g1) { g1 = g[e]; i1 = e; }
  int i2 = -1; float g2 = -1e30f;
#pragma unroll
  for (int e = 0; e < NE; ++e) if (e != i1 && g[e] > g2) { g2 = g[e]; i2 = e; }
  float wa = 1.0f / (1.0f + expf(g2 - g1));  // softmax+renorm over top-2
  float wb = 1.0f - wa;
  int s1 = atomicAdd(&counts[i1], 1);
  tok_idx[i1 * T_TOK + s1] = t; tok_w[i1 * T_TOK + s1] = wa; tok_cpy[i1 * T_TOK + s1] = 0;
  int s2 = atomicAdd(&counts[i2], 1);
  tok_idx[i2 * T_TOK + s2] = t; tok_w[i2 * T_TOK + s2] = wb; tok_cpy[i2 * T_TOK + s2] = 1;
}

// ---------------- pack token copies -> compact bf16 rows ----------------
__global__ void k_pack(const float* __restrict__ hs, const int* __restrict__ counts,
                       const int* __restrict__ tok_idx, const float* __restrict__ tok_w,
                       const int* __restrict__ tok_cpy, unsigned short* __restrict__ xpack,
                       int* __restrict__ row_tok, float* __restrict__ row_w,
                       int* __restrict__ inv_row) {
  int e = blockIdx.x >> 10, slot = blockIdx.x & 1023;
  if (slot >= counts[e]) return;
  int off = 0;
#pragma unroll
  for (int i = 0; i < NE; ++i) if (i < e) off += counts[i];
  int row = off + slot;
  int tok = tok_idx[e * T_TOK + slot];
  if (threadIdx.x == 0) {
    row_tok[row] = tok;
    row_w[row] = tok_w[e * T_TOK + slot];
    inv_row[tok * 2 + tok_cpy[e * T_TOK + slot]] = row;
  }
  float4 v = ((const float4*)(hs + (size_t)tok * H_DIM))[threadIdx.x];
  ushort4 o = make_ushort4(f2bf(v.x), f2bf(v.y), f2bf(v.z), f2bf(v.w));
  ((ushort4*)(xpack + (size_t)row * H_DIM))[threadIdx.x] = o;
}

#define BK 64

// ---------------- grouped GEMM1 + SwiGLU: 128x128 tile ----------------
// B-tile: 128 w1 rows = 64 gate + 64 up interleaved by 16-row frag parity.
// waves 2x2, each wave 64x64 -> acc[4][4]. Grid encodes XCD panel clustering:
// b = ((pl*8 + mt)<<3)|x ; panel = pl*8+x ; mtiles of a panel consecutive per XCD.
__global__ __launch_bounds__(256, 2)
void k_gemm1(const float* __restrict__ w1, const unsigned short* __restrict__ xpack,
             const int* __restrict__ counts, unsigned short* __restrict__ act) {
  int b = blockIdx.x;
  int x = b & 7, s = b >> 3;
  int mt = s & 7, pl = s >> 3;
  int panel = pl * 8 + x;           // [0,512)
  int e = panel >> 6, ntile = panel & 63;
  int cnt = counts[e];
  int m0 = mt * 128;
  if (m0 >= cnt) return;
  int off = 0;
#pragma unroll
  for (int i = 0; i < NE; ++i) if (i < e) off += counts[i];
  int n0 = ntile * 64;

  __shared__ __align__(16) short As[128 * BK];
  __shared__ __align__(16) short Bs[128 * BK];

  int tid = threadIdx.x;
  int lane = tid & 63, wid = tid >> 6;
  int wm = wid & 1, wn = wid >> 1;
  int lr = lane & 15, lk8 = (lane >> 4) * 8;

  const float* w1e = w1 + (size_t)e * (2 * I_DIM) * H_DIM;
  const unsigned short* xb = xpack + (size_t)(off + m0) * H_DIM;

  int arow0 = tid >> 3, ack = tid & 7;   // A: 4 x us8 (rows arow0 + i*32)
  int brow0 = tid >> 4, bck = tid & 15;  // B: 8 x float4 (rows brow0 + i*16)

  f32x4 acc[4][4];
#pragma unroll
  for (int i = 0; i < 4; ++i)
#pragma unroll
    for (int j = 0; j < 4; ++j) acc[i][j] = (f32x4){0.f, 0.f, 0.f, 0.f};

  us8 aReg[4];
  float4 bReg[8];

  auto loadA = [&](int k0) {
#pragma unroll
    for (int i = 0; i < 4; ++i) {
      int r = arow0 + i * 32;
      us8 z = {0, 0, 0, 0, 0, 0, 0, 0};
      aReg[i] = (m0 + r < cnt) ? *(const us8*)(xb + (size_t)r * H_DIM + k0 + ack * 8) : z;
    }
  };
  auto loadB = [&](int k0) {
#pragma unroll
    for (int i = 0; i < 8; ++i) {
      int r = brow0 + i * 16;
      int grow = ((r & 16) ? I_DIM : 0) + n0 + ((r >> 5) << 4) + (r & 15);
      bReg[i] = *(const float4*)(w1e + (size_t)grow * H_DIM + k0 + bck * 4);
    }
  };

  loadA(0); loadB(0);

  for (int ks = 0; ks < H_DIM / BK; ++ks) {
    __syncthreads();
#pragma unroll
    for (int i = 0; i < 4; ++i) {
      int r = arow0 + i * 32;
      *(us8*)&As[r * BK + ((ack * 8) ^ ((r & 7) << 3))] = aReg[i];
    }
#pragma unroll
    for (int i = 0; i < 8; ++i) {
      int r = brow0 + i * 16;
      float4 v = bReg[i];
      s16x4 sv = {(short)f2bf(v.x), (short)f2bf(v.y), (short)f2bf(v.z), (short)f2bf(v.w)};
      *(s16x4*)&Bs[r * BK + ((bck * 4) ^ ((r & 7) << 3))] = sv;
    }
    __syncthreads();
    if (ks + 1 < H_DIM / BK) { loadA((ks + 1) * BK); loadB((ks + 1) * BK); }
#pragma unroll
    for (int kk = 0; kk < 2; ++kk) {
      int k0 = kk * 32 + lk8;
      bf16x8 a[4], bb[4];
#pragma unroll
      for (int mr = 0; mr < 4; ++mr) {
        int r = wm * 64 + mr * 16 + lr;
        a[mr] = *(const bf16x8*)&As[r * BK + (k0 ^ ((r & 7) << 3))];
      }
#pragma unroll
      for (int nr = 0; nr < 4; ++nr) {
        int r = wn * 64 + nr * 16 + lr;
        bb[nr] = *(const bf16x8*)&Bs[r * BK + (k0 ^ ((r & 7) << 3))];
      }
#pragma unroll
      for (int mr = 0; mr < 4; ++mr)
#pragma unroll
        for (int nr = 0; nr < 4; ++nr)
          acc[mr][nr] = __builtin_amdgcn_mfma_f32_16x16x32_bf16(a[mr], bb[nr], acc[mr][nr], 0, 0, 0);
    }
  }

  // SwiGLU: frag f = wn*4+nr; parity f&1 = gate/up; col = n0 + (f>>1)*16 + lr
#pragma unroll
  for (int mr = 0; mr < 4; ++mr) {
#pragma unroll
    for (int pp = 0; pp < 2; ++pp) {
      f32x4 g = acc[mr][2 * pp], u = acc[mr][2 * pp + 1];
      int ncol = n0 + (wn * 2 + pp) * 16 + lr;
#pragma unroll
      for (int q = 0; q < 4; ++q) {
        int rl = wm * 64 + mr * 16 + (lane >> 4) * 4 + q;
        if (m0 + rl < cnt) {
          float gv = g[q];
          float av = gv / (1.0f + expf(-gv)) * u[q];
          act[(size_t)(off + m0 + rl) * I_DIM + ncol] = f2bf(av);
        }
      }
    }
  }
}

// ---------------- grouped GEMM2 + scale -> y scratch (no atomics) ----------------
// BM=64, BN=128. Grid: b = ((pl*16+mt)<<3)|x ; e = pl, ntile = x.
__global__ __launch_bounds__(256, 2)
void k_gemm2(const float* __restrict__ w2, const unsigned short* __restrict__ act,
             const int* __restrict__ counts, const float* __restrict__ row_w,
             float* __restrict__ y) {
  int b = blockIdx.x;
  int x = b & 7, s = b >> 3;
  int mt = s & 15, e = s >> 4;
  int ntile = x;
  int cnt = counts[e];
  int m0 = mt * 64;
  if (m0 >= cnt) return;
  int off = 0;
#pragma unroll
  for (int i = 0; i < NE; ++i) if (i < e) off += counts[i];
  int n0 = ntile * 128;

  __shared__ __align__(16) short As[64 * BK];
  __shared__ __align__(16) short Bs[128 * BK];

  int tid = threadIdx.x;
  int lane = tid & 63, wid = tid >> 6;
  int wm = wid & 1, wn = wid >> 1;
  int lr = lane & 15, lk8 = (lane >> 4) * 8;

  const float* w2e = w2 + (size_t)e * H_DIM * I_DIM;
  const unsigned short* ab = act + (size_t)(off + m0) * I_DIM;

  int arow0 = tid >> 3, ack = tid & 7;
  int brow0 = tid >> 4, bck = tid & 15;

  f32x4 acc[2][4];
#pragma unroll
  for (int i = 0; i < 2; ++i)
#pragma unroll
    for (int j = 0; j < 4; ++j) acc[i][j] = (f32x4){0.f, 0.f, 0.f, 0.f};

  us8 aReg[2];
  float4 bReg[8];

  auto loadA = [&](int k0) {
#pragma unroll
    for (int i = 0; i < 2; ++i) {
      int r = arow0 + i * 32;
      us8 z = {0, 0, 0, 0, 0, 0, 0, 0};
      aReg[i] = (m0 + r < cnt) ? *(const us8*)(ab + (size_t)r * I_DIM + k0 + ack * 8) : z;
    }
  };
  auto loadB = [&](int k0) {
#pragma unroll
    for (int i = 0; i < 8; ++i) {
      int r = brow0 + i * 16;
      bReg[i] = *(const float4*)(w2e + (size_t)(n0 + r) * I_DIM + k0 + bck * 4);
    }
  };

  loadA(0); loadB(0);

  for (int ks = 0; ks < I_DIM / BK; ++ks) {
    __syncthreads();
#pragma unroll
    for (int i = 0; i < 2; ++i) {
      int r = arow0 + i * 32;
      *(us8*)&As[r * BK + ((ack * 8) ^ ((r & 7) << 3))] = aReg[i];
    }
#pragma unroll
    for (int i = 0; i < 8; ++i) {
      int r = brow0 + i * 16;
      float4 v = bReg[i];
      s16x4 sv = {(short)f2bf(v.x), (short)f2bf(v.y), (short)f2bf(v.z), (short)f2bf(v.w)};
      *(s16x4*)&Bs[r * BK + ((bck * 4) ^ ((r & 7) << 3))] = sv;
    }
    __syncthreads();
    if (ks + 1 < I_DIM / BK) { loadA((ks + 1) * BK); loadB((ks + 1) * BK); }
#pragma unroll
    for (int kk = 0; kk < 2; ++kk) {
      int k0 = kk * 32 + lk8;
      bf16x8 a[2], bb[4];
#pragma unroll
      for (int mr = 0; mr < 2; ++mr) {
        int r = wm * 32 + mr * 16 + lr;
        a[mr] = *(const bf16x8*)&As[r * BK + (k0 ^ ((r & 7) << 3))];
      }
#pragma unroll
      for (int nr = 0; nr < 4; ++nr) {
        int r = (wn * 4 + nr) * 16 + lr;
        bb[nr] = *(const bf16x8*)&Bs[r * BK + (k0 ^ ((r & 7) << 3))];
      }
#pragma unroll
      for (int mr = 0; mr < 2; ++mr)
#pragma unroll
        for (int nr = 0; nr < 4; ++nr)
          acc[mr][nr] = __builtin_amdgcn_mfma_f32_16x16x32_bf16(a[mr], bb[nr], acc[mr][nr], 0, 0, 0);
    }
  }

#pragma unroll
  for (int mr = 0; mr < 2; ++mr) {
#pragma unroll
    for (int q = 0; q < 4; ++q) {
      int rl = wm * 32 + mr * 16 + (lane >> 4) * 4 + q;
      if (m0 + rl >= cnt) continue;
      int grow = off + m0 + rl;
      float wgt = row_w[grow];
      float* yrow = y + (size_t)grow * H_DIM;
#pragma unroll
      for (int nr = 0; nr < 4; ++nr) {
        int ncol = n0 + (wn * 4 + nr) * 16 + lr;
        yrow[ncol] = acc[mr][nr][q] * wgt;
      }
    }
  }
}

// ---------------- combine: out[t] = y[inv0] + y[inv1] ----------------
__global__ void k_combine(const float* __restrict__ y, const int* __restrict__ inv_row,
                          float* __restrict__ out) {
  int t = blockIdx.x, i = threadIdx.x;
  const float4* ya = (const float4*)(y + (size_t)inv_row[2 * t] * H_DIM);
  const float4* yb = (const float4*)(y + (size_t)inv_row[2 * t + 1] * H_DIM);
  float4 a = ya[i], b2 = yb[i];
  ((float4*)(out + (size_t)t * H_DIM))[i] =
      make_float4(a.x + b2.x, a.y + b2.y, a.z + b2.z, a.w + b2.w);
}

extern "C" void kernel_launch(void* const* d_in, const int* in_sizes, int n_in,
                              void* d_out, int out_size, void* d_ws, size_t ws_size,
                              hipStream_t stream) {
  const float* hs = (const float*)d_in[0];
  const float* w1 = (const float*)d_in[1];
  const float* w2 = (const float*)d_in[2];
  const float* gates = (const float*)d_in[3];
  float* out = (float*)d_out;

  char* ws = (char*)d_ws;
  int* counts = (int*)ws;                                // 32 B
  int* tok_idx = (int*)(ws + 4096);                      // 32 KB
  float* tok_w = (float*)(ws + 4096 + 32768);            // 32 KB
  int* tok_cpy = (int*)(ws + 4096 + 65536);              // 32 KB
  int* row_tok = (int*)(ws + 4096 + 98304);              // 8 KB
  float* row_w = (float*)(ws + 4096 + 98304 + 8192);     // 8 KB
  int* inv_row = (int*)(ws + 4096 + 98304 + 16384);      // 8 KB
  unsigned short* xpack = (unsigned short*)(ws + (1 << 17));       // 4 MB
  unsigned short* act = (unsigned short*)(ws + (8u << 20));        // 16 MB
  float* y = (float*)(ws + (32u << 20));                           // 8 MB

  hipMemsetAsync(counts, 0, NE * sizeof(int), stream);
  k_route<<<dim3(4), dim3(256), 0, stream>>>(gates, counts, tok_idx, tok_w, tok_cpy);
  k_pack<<<dim3(NE * T_TOK), dim3(256), 0, stream>>>(hs, counts, tok_idx, tok_w, tok_cpy,
                                                     xpack, row_tok, row_w, inv_row);
  k_gemm1<<<dim3(4096), dim3(256), 0, stream>>>(w1, xpack, counts, act);
  k_gemm2<<<dim3(1024), dim3(256), 0, stream>>>(w2, act, counts, row_w, y);
  k_combine<<<dim3(T_TOK), dim3(256), 0, stream>>>(y, inv_row, out);
}

// Round 3
// 258.203 us; speedup vs baseline: 1.0868x; 1.0868x over previous
//
#include <hip/hip_runtime.h>

#define T_TOK 1024
#define H_DIM 1024
#define I_DIM 4096
#define NE 8

typedef __attribute__((ext_vector_type(8))) short bf16x8;
typedef __attribute__((ext_vector_type(4))) float f32x4;
typedef __attribute__((ext_vector_type(8))) unsigned short us8;

__device__ __forceinline__ unsigned short f2bf(float x) {
  union { float f; unsigned u; } v; v.f = x;
  unsigned r = v.u + 0x7fffu + ((v.u >> 16) & 1u);  // RNE
  return (unsigned short)(r >> 16);
}

// HW packed fp32->bf16 (RNE): lo16 = bf16(a), hi16 = bf16(b)
__device__ __forceinline__ unsigned cvt_pk_bf16(float a, float b) {
  unsigned r;
  asm("v_cvt_pk_bf16_f32 %0, %1, %2" : "=v"(r) : "v"(a), "v"(b));
  return r;
}

// ---------------- routing: softmax top-2 + renormalize ----------------
__global__ void k_route(const float* __restrict__ gates, int* __restrict__ counts,
                        int* __restrict__ tok_idx, float* __restrict__ tok_w,
                        int* __restrict__ tok_cpy) {
  int t = blockIdx.x * blockDim.x + threadIdx.x;
  if (t >= T_TOK) return;
  float g[NE];
#pragma unroll
  for (int e = 0; e < NE; ++e) g[e] = gates[t * NE + e];
  int i1 = 0; float g1 = g[0];
#pragma unroll
  for (int e = 1; e < NE; ++e) if (g[e] > g1) { g1 = g[e]; i1 = e; }
  int i2 = -1; float g2 = -1e30f;
#pragma unroll
  for (int e = 0; e < NE; ++e) if (e != i1 && g[e] > g2) { g2 = g[e]; i2 = e; }
  float wa = 1.0f / (1.0f + expf(g2 - g1));  // softmax+renorm over top-2
  float wb = 1.0f - wa;
  int s1 = atomicAdd(&counts[i1], 1);
  tok_idx[i1 * T_TOK + s1] = t; tok_w[i1 * T_TOK + s1] = wa; tok_cpy[i1 * T_TOK + s1] = 0;
  int s2 = atomicAdd(&counts[i2], 1);
  tok_idx[i2 * T_TOK + s2] = t; tok_w[i2 * T_TOK + s2] = wb; tok_cpy[i2 * T_TOK + s2] = 1;
}

// ---------------- pack token copies -> compact bf16 rows ----------------
__global__ void k_pack(const float* __restrict__ hs, const int* __restrict__ counts,
                       const int* __restrict__ tok_idx, const float* __restrict__ tok_w,
                       const int* __restrict__ tok_cpy, unsigned short* __restrict__ xpack,
                       int* __restrict__ row_tok, float* __restrict__ row_w,
                       int* __restrict__ inv_row) {
  int e = blockIdx.x >> 10, slot = blockIdx.x & 1023;
  if (slot >= counts[e]) return;
  int off = 0;
#pragma unroll
  for (int i = 0; i < NE; ++i) if (i < e) off += counts[i];
  int row = off + slot;
  int tok = tok_idx[e * T_TOK + slot];
  if (threadIdx.x == 0) {
    row_tok[row] = tok;
    row_w[row] = tok_w[e * T_TOK + slot];
    inv_row[tok * 2 + tok_cpy[e * T_TOK + slot]] = row;
  }
  float4 v = ((const float4*)(hs + (size_t)tok * H_DIM))[threadIdx.x];
  uint2 o; o.x = cvt_pk_bf16(v.x, v.y); o.y = cvt_pk_bf16(v.z, v.w);
  ((uint2*)(xpack + (size_t)row * H_DIM))[threadIdx.x] = o;
}

#define BK 64

// ---------------- grouped GEMM1 + SwiGLU: 128x128 tile ----------------
__global__ __launch_bounds__(256)
void k_gemm1(const float* __restrict__ w1, const unsigned short* __restrict__ xpack,
             const int* __restrict__ counts, unsigned short* __restrict__ act) {
  int b = blockIdx.x;
  int x = b & 7, s = b >> 3;
  int mt = s & 7, pl = s >> 3;
  int panel = pl * 8 + x;           // [0,512)
  int e = panel >> 6, ntile = panel & 63;
  int cnt = counts[e];
  int m0 = mt * 128;
  if (m0 >= cnt) return;
  int off = 0;
#pragma unroll
  for (int i = 0; i < NE; ++i) if (i < e) off += counts[i];
  int n0 = ntile * 64;

  __shared__ __align__(16) short As[128 * BK];
  __shared__ __align__(16) short Bs[128 * BK];

  int tid = threadIdx.x;
  int lane = tid & 63, wid = tid >> 6;
  int wm = wid & 1, wn = wid >> 1;
  int lr = lane & 15, lk8 = (lane >> 4) * 8;

  const float* w1e = w1 + (size_t)e * (2 * I_DIM) * H_DIM;
  const unsigned short* xb = xpack + (size_t)(off + m0) * H_DIM;

  int arow0 = tid >> 3, ack = tid & 7;   // A: 4 x us8 (rows arow0 + i*32)
  int brow0 = tid >> 4, bck = tid & 15;  // B: 8 x float4 (rows brow0 + i*16)

  // hoisted per-row source pointers and LDS byte-offsets
  const unsigned short* aptr[4];
  int awoff[4];
#pragma unroll
  for (int i = 0; i < 4; ++i) {
    int r = arow0 + i * 32;
    aptr[i] = xb + (size_t)r * H_DIM + ack * 8;
    awoff[i] = r * BK + ((ack * 8) ^ ((r & 7) << 3));
  }
  const float* bptr[8];
  int bwoff[8];
#pragma unroll
  for (int i = 0; i < 8; ++i) {
    int r = brow0 + i * 16;
    int grow = ((r & 16) ? I_DIM : 0) + n0 + ((r >> 5) << 4) + (r & 15);
    bptr[i] = w1e + (size_t)grow * H_DIM + bck * 4;
    bwoff[i] = r * BK + ((bck * 4) ^ ((r & 7) << 3));
  }

  f32x4 acc[4][4];
#pragma unroll
  for (int i = 0; i < 4; ++i)
#pragma unroll
    for (int j = 0; j < 4; ++j) acc[i][j] = (f32x4){0.f, 0.f, 0.f, 0.f};

  us8 aReg[4];
  float4 bReg[8];

  auto loadA = [&](int k0) {
#pragma unroll
    for (int i = 0; i < 4; ++i) {
      us8 z = {0, 0, 0, 0, 0, 0, 0, 0};
      aReg[i] = (m0 + arow0 + i * 32 < cnt) ? *(const us8*)(aptr[i] + k0) : z;
    }
  };
  auto loadB = [&](int k0) {
#pragma unroll
    for (int i = 0; i < 8; ++i) bReg[i] = *(const float4*)(bptr[i] + k0);
  };

  loadA(0); loadB(0);

  for (int ks = 0; ks < H_DIM / BK; ++ks) {
    __syncthreads();
#pragma unroll
    for (int i = 0; i < 4; ++i) *(us8*)&As[awoff[i]] = aReg[i];
#pragma unroll
    for (int i = 0; i < 8; ++i) {
      float4 v = bReg[i];
      uint2 o; o.x = cvt_pk_bf16(v.x, v.y); o.y = cvt_pk_bf16(v.z, v.w);
      *(uint2*)&Bs[bwoff[i]] = o;
    }
    __syncthreads();
    if (ks + 1 < H_DIM / BK) { loadA((ks + 1) * BK); loadB((ks + 1) * BK); }
#pragma unroll
    for (int kk = 0; kk < 2; ++kk) {
      int k0 = kk * 32 + lk8;
      bf16x8 a[4], bb[4];
#pragma unroll
      for (int mr = 0; mr < 4; ++mr) {
        int r = wm * 64 + mr * 16 + lr;
        a[mr] = *(const bf16x8*)&As[r * BK + (k0 ^ ((r & 7) << 3))];
      }
#pragma unroll
      for (int nr = 0; nr < 4; ++nr) {
        int r = wn * 64 + nr * 16 + lr;
        bb[nr] = *(const bf16x8*)&Bs[r * BK + (k0 ^ ((r & 7) << 3))];
      }
#pragma unroll
      for (int mr = 0; mr < 4; ++mr)
#pragma unroll
        for (int nr = 0; nr < 4; ++nr)
          acc[mr][nr] = __builtin_amdgcn_mfma_f32_16x16x32_bf16(a[mr], bb[nr], acc[mr][nr], 0, 0, 0);
    }
  }

  // SwiGLU: frag f = wn*4+nr; parity f&1 = gate/up; col = n0 + (f>>1)*16 + lr
#pragma unroll
  for (int mr = 0; mr < 4; ++mr) {
#pragma unroll
    for (int pp = 0; pp < 2; ++pp) {
      f32x4 g = acc[mr][2 * pp], u = acc[mr][2 * pp + 1];
      int ncol = n0 + (wn * 2 + pp) * 16 + lr;
#pragma unroll
      for (int q = 0; q < 4; ++q) {
        int rl = wm * 64 + mr * 16 + (lane >> 4) * 4 + q;
        if (m0 + rl < cnt) {
          float gv = g[q];
          float av = gv / (1.0f + expf(-gv)) * u[q];
          act[(size_t)(off + m0 + rl) * I_DIM + ncol] = f2bf(av);
        }
      }
    }
  }
}

// ---------------- grouped GEMM2 + scale -> y scratch (no atomics) ----------------
__global__ __launch_bounds__(256)
void k_gemm2(const float* __restrict__ w2, const unsigned short* __restrict__ act,
             const int* __restrict__ counts, const float* __restrict__ row_w,
             float* __restrict__ y) {
  int b = blockIdx.x;
  int x = b & 7, s = b >> 3;
  int mt = s & 15, e = s >> 4;
  int ntile = x;
  int cnt = counts[e];
  int m0 = mt * 64;
  if (m0 >= cnt) return;
  int off = 0;
#pragma unroll
  for (int i = 0; i < NE; ++i) if (i < e) off += counts[i];
  int n0 = ntile * 128;

  __shared__ __align__(16) short As[64 * BK];
  __shared__ __align__(16) short Bs[128 * BK];

  int tid = threadIdx.x;
  int lane = tid & 63, wid = tid >> 6;
  int wm = wid & 1, wn = wid >> 1;
  int lr = lane & 15, lk8 = (lane >> 4) * 8;

  const float* w2e = w2 + (size_t)e * H_DIM * I_DIM;
  const unsigned short* ab = act + (size_t)(off + m0) * I_DIM;

  int arow0 = tid >> 3, ack = tid & 7;
  int brow0 = tid >> 4, bck = tid & 15;

  const unsigned short* aptr[2];
  int awoff[2];
#pragma unroll
  for (int i = 0; i < 2; ++i) {
    int r = arow0 + i * 32;
    aptr[i] = ab + (size_t)r * I_DIM + ack * 8;
    awoff[i] = r * BK + ((ack * 8) ^ ((r & 7) << 3));
  }
  const float* bptr[8];
  int bwoff[8];
#pragma unroll
  for (int i = 0; i < 8; ++i) {
    int r = brow0 + i * 16;
    bptr[i] = w2e + (size_t)(n0 + r) * I_DIM + bck * 4;
    bwoff[i] = r * BK + ((bck * 4) ^ ((r & 7) << 3));
  }

  f32x4 acc[2][4];
#pragma unroll
  for (int i = 0; i < 2; ++i)
#pragma unroll
    for (int j = 0; j < 4; ++j) acc[i][j] = (f32x4){0.f, 0.f, 0.f, 0.f};

  us8 aReg[2];
  float4 bReg[8];

  auto loadA = [&](int k0) {
#pragma unroll
    for (int i = 0; i < 2; ++i) {
      us8 z = {0, 0, 0, 0, 0, 0, 0, 0};
      aReg[i] = (m0 + arow0 + i * 32 < cnt) ? *(const us8*)(aptr[i] + k0) : z;
    }
  };
  auto loadB = [&](int k0) {
#pragma unroll
    for (int i = 0; i < 8; ++i) bReg[i] = *(const float4*)(bptr[i] + k0);
  };

  loadA(0); loadB(0);

  for (int ks = 0; ks < I_DIM / BK; ++ks) {
    __syncthreads();
#pragma unroll
    for (int i = 0; i < 2; ++i) *(us8*)&As[awoff[i]] = aReg[i];
#pragma unroll
    for (int i = 0; i < 8; ++i) {
      float4 v = bReg[i];
      uint2 o; o.x = cvt_pk_bf16(v.x, v.y); o.y = cvt_pk_bf16(v.z, v.w);
      *(uint2*)&Bs[bwoff[i]] = o;
    }
    __syncthreads();
    if (ks + 1 < I_DIM / BK) { loadA((ks + 1) * BK); loadB((ks + 1) * BK); }
#pragma unroll
    for (int kk = 0; kk < 2; ++kk) {
      int k0 = kk * 32 + lk8;
      bf16x8 a[2], bb[4];
#pragma unroll
      for (int mr = 0; mr < 2; ++mr) {
        int r = wm * 32 + mr * 16 + lr;
        a[mr] = *(const bf16x8*)&As[r * BK + (k0 ^ ((r & 7) << 3))];
      }
#pragma unroll
      for (int nr = 0; nr < 4; ++nr) {
        int r = (wn * 4 + nr) * 16 + lr;
        bb[nr] = *(const bf16x8*)&Bs[r * BK + (k0 ^ ((r & 7) << 3))];
      }
#pragma unroll
      for (int mr = 0; mr < 2; ++mr)
#pragma unroll
        for (int nr = 0; nr < 4; ++nr)
          acc[mr][nr] = __builtin_amdgcn_mfma_f32_16x16x32_bf16(a[mr], bb[nr], acc[mr][nr], 0, 0, 0);
    }
  }

#pragma unroll
  for (int mr = 0; mr < 2; ++mr) {
#pragma unroll
    for (int q = 0; q < 4; ++q) {
      int rl = wm * 32 + mr * 16 + (lane >> 4) * 4 + q;
      if (m0 + rl >= cnt) continue;
      int grow = off + m0 + rl;
      float wgt = row_w[grow];
      float* yrow = y + (size_t)grow * H_DIM;
#pragma unroll
      for (int nr = 0; nr < 4; ++nr) {
        int ncol = n0 + (wn * 4 + nr) * 16 + lr;
        yrow[ncol] = acc[mr][nr][q] * wgt;
      }
    }
  }
}

// ---------------- combine: out[t] = y[inv0] + y[inv1] ----------------
__global__ void k_combine(const float* __restrict__ y, const int* __restrict__ inv_row,
                          float* __restrict__ out) {
  int t = blockIdx.x, i = threadIdx.x;
  const float4* ya = (const float4*)(y + (size_t)inv_row[2 * t] * H_DIM);
  const float4* yb = (const float4*)(y + (size_t)inv_row[2 * t + 1] * H_DIM);
  float4 a = ya[i], b2 = yb[i];
  ((float4*)(out + (size_t)t * H_DIM))[i] =
      make_float4(a.x + b2.x, a.y + b2.y, a.z + b2.z, a.w + b2.w);
}

extern "C" void kernel_launch(void* const* d_in, const int* in_sizes, int n_in,
                              void* d_out, int out_size, void* d_ws, size_t ws_size,
                              hipStream_t stream) {
  const float* hs = (const float*)d_in[0];
  const float* w1 = (const float*)d_in[1];
  const float* w2 = (const float*)d_in[2];
  const float* gates = (const float*)d_in[3];
  float* out = (float*)d_out;

  char* ws = (char*)d_ws;
  int* counts = (int*)ws;                                // 32 B
  int* tok_idx = (int*)(ws + 4096);                      // 32 KB
  float* tok_w = (float*)(ws + 4096 + 32768);            // 32 KB
  int* tok_cpy = (int*)(ws + 4096 + 65536);              // 32 KB
  int* row_tok = (int*)(ws + 4096 + 98304);              // 8 KB
  float* row_w = (float*)(ws + 4096 + 98304 + 8192);     // 8 KB
  int* inv_row = (int*)(ws + 4096 + 98304 + 16384);      // 8 KB
  unsigned short* xpack = (unsigned short*)(ws + (1 << 17));       // 4 MB
  unsigned short* act = (unsigned short*)(ws + (8u << 20));        // 16 MB
  float* y = (float*)(ws + (32u << 20));                           // 8 MB

  hipMemsetAsync(counts, 0, NE * sizeof(int), stream);
  k_route<<<dim3(4), dim3(256), 0, stream>>>(gates, counts, tok_idx, tok_w, tok_cpy);
  k_pack<<<dim3(NE * T_TOK), dim3(256), 0, stream>>>(hs, counts, tok_idx, tok_w, tok_cpy,
                                                     xpack, row_tok, row_w, inv_row);
  k_gemm1<<<dim3(4096), dim3(256), 0, stream>>>(w1, xpack, counts, act);
  k_gemm2<<<dim3(1024), dim3(256), 0, stream>>>(w2, act, counts, row_w, y);
  k_combine<<<dim3(T_TOK), dim3(256), 0, stream>>>(y, inv_row, out);
}

// Round 4
// 222.113 us; speedup vs baseline: 1.2634x; 1.1625x over previous
//
#include <hip/hip_runtime.h>

#define T_TOK 1024
#define H_DIM 1024
#define I_DIM 4096
#define NE 8

typedef __attribute__((ext_vector_type(8))) short bf16x8;
typedef __attribute__((ext_vector_type(4))) float f32x4;
typedef __attribute__((ext_vector_type(8))) unsigned short us8;

__device__ __forceinline__ unsigned short f2bf(float x) {
  union { float f; unsigned u; } v; v.f = x;
  unsigned r = v.u + 0x7fffu + ((v.u >> 16) & 1u);  // RNE
  return (unsigned short)(r >> 16);
}

__device__ __forceinline__ unsigned cvt_pk_bf16(float a, float b) {
  unsigned r;
  asm("v_cvt_pk_bf16_f32 %0, %1, %2" : "=v"(r) : "v"(a), "v"(b));
  return r;
}

// ---------------- routing: softmax top-2 + renormalize ----------------
__global__ void k_route(const float* __restrict__ gates, int* __restrict__ counts,
                        int* __restrict__ tok_idx, float* __restrict__ tok_w,
                        int* __restrict__ tok_cpy) {
  int t = blockIdx.x * blockDim.x + threadIdx.x;
  if (t >= T_TOK) return;
  float g[NE];
#pragma unroll
  for (int e = 0; e < NE; ++e) g[e] = gates[t * NE + e];
  int i1 = 0; float g1 = g[0];
#pragma unroll
  for (int e = 1; e < NE; ++e) if (g[e] > g1) { g1 = g[e]; i1 = e; }
  int i2 = -1; float g2 = -1e30f;
#pragma unroll
  for (int e = 0; e < NE; ++e) if (e != i1 && g[e] > g2) { g2 = g[e]; i2 = e; }
  float wa = 1.0f / (1.0f + expf(g2 - g1));
  float wb = 1.0f - wa;
  int s1 = atomicAdd(&counts[i1], 1);
  tok_idx[i1 * T_TOK + s1] = t; tok_w[i1 * T_TOK + s1] = wa; tok_cpy[i1 * T_TOK + s1] = 0;
  int s2 = atomicAdd(&counts[i2], 1);
  tok_idx[i2 * T_TOK + s2] = t; tok_w[i2 * T_TOK + s2] = wb; tok_cpy[i2 * T_TOK + s2] = 1;
}

// ---------------- pack token copies -> compact bf16 rows ----------------
__global__ void k_pack(const float* __restrict__ hs, const int* __restrict__ counts,
                       const int* __restrict__ tok_idx, const float* __restrict__ tok_w,
                       const int* __restrict__ tok_cpy, unsigned short* __restrict__ xpack,
                       float* __restrict__ row_w, int* __restrict__ inv_row) {
  int e = blockIdx.x >> 10, slot = blockIdx.x & 1023;
  if (slot >= counts[e]) return;
  int off = 0;
#pragma unroll
  for (int i = 0; i < NE; ++i) if (i < e) off += counts[i];
  int row = off + slot;
  int tok = tok_idx[e * T_TOK + slot];
  if (threadIdx.x == 0) {
    row_w[row] = tok_w[e * T_TOK + slot];
    inv_row[tok * 2 + tok_cpy[e * T_TOK + slot]] = row;
  }
  float4 v = ((const float4*)(hs + (size_t)tok * H_DIM))[threadIdx.x];
  uint2 o; o.x = cvt_pk_bf16(v.x, v.y); o.y = cvt_pk_bf16(v.z, v.w);
  ((uint2*)(xpack + (size_t)row * H_DIM))[threadIdx.x] = o;
}

#define BK 64

// ---------------- grouped GEMM1 + SwiGLU: 128 tokens x 32 act-cols ----------------
// B-tile: 64 w1 rows (32 gate + 32 up interleaved per 16-row frag).
// 4 waves 2x2: wave = 64 tokens x 32 w1-rows -> acc[4][2].
// grid 8192: b=((pl*8+mt)<<3)|x, panel=pl*8+x in [0,1024), mt in [0,8).
__global__ __launch_bounds__(256)
void k_gemm1(const float* __restrict__ w1, const unsigned short* __restrict__ xpack,
             const int* __restrict__ counts, unsigned short* __restrict__ act) {
  int b = blockIdx.x;
  int x = b & 7, s = b >> 3;
  int mt = s & 7, pl = s >> 3;          // pl in [0,128)
  int panel = pl * 8 + x;               // [0,1024)
  int e = panel >> 7, ntile = panel & 127;
  int cnt = counts[e];
  int m0 = mt * 128;
  if (m0 >= cnt) return;
  int off = 0;
#pragma unroll
  for (int i = 0; i < NE; ++i) if (i < e) off += counts[i];
  int n0 = ntile * 32;                  // act column base

  __shared__ __align__(16) short As[128 * BK];  // 16 KB
  __shared__ __align__(16) short Bs[64 * BK];   // 8 KB

  int tid = threadIdx.x;
  int lane = tid & 63, wid = tid >> 6;
  int wm = wid & 1, wn = wid >> 1;      // wn in [0,2)
  int lr = lane & 15, lk8 = (lane >> 4) * 8;

  const float* w1e = w1 + (size_t)e * (2 * I_DIM) * H_DIM;
  const unsigned short* xb = xpack + (size_t)(off + m0) * H_DIM;

  int arow0 = tid >> 3, ack = tid & 7;   // A: 4 chunks, rows arow0+i*32
  int brow0 = tid >> 4, bck = tid & 15;  // B: 4 chunks, rows brow0+i*16

  const unsigned short* aptr[4];
  int awoff[4];
#pragma unroll
  for (int i = 0; i < 4; ++i) {
    int r = arow0 + i * 32;
    aptr[i] = xb + (size_t)r * H_DIM + ack * 8;
    awoff[i] = r * BK + ((ack * 8) ^ ((r & 7) << 3));
  }
  const float* bptr[4];
  int bwoff[4];
#pragma unroll
  for (int i = 0; i < 4; ++i) {
    int r = brow0 + i * 16;
    int grow = ((r & 16) ? I_DIM : 0) + n0 + ((r >> 5) << 4) + (r & 15);
    bptr[i] = w1e + (size_t)grow * H_DIM + bck * 4;
    bwoff[i] = r * BK + ((bck * 4) ^ ((r & 7) << 3));
  }

  f32x4 acc[4][2];
#pragma unroll
  for (int i = 0; i < 4; ++i)
#pragma unroll
    for (int j = 0; j < 2; ++j) acc[i][j] = (f32x4){0.f, 0.f, 0.f, 0.f};

  us8 aReg[4];
  float4 bReg[4];

  auto loadA = [&](int k0) {
#pragma unroll
    for (int i = 0; i < 4; ++i) {
      us8 z = {0, 0, 0, 0, 0, 0, 0, 0};
      aReg[i] = (m0 + arow0 + i * 32 < cnt) ? *(const us8*)(aptr[i] + k0) : z;
    }
  };
  auto loadB = [&](int k0) {
#pragma unroll
    for (int i = 0; i < 4; ++i) bReg[i] = *(const float4*)(bptr[i] + k0);
  };

  loadA(0); loadB(0);

  for (int ks = 0; ks < H_DIM / BK; ++ks) {
    __syncthreads();
#pragma unroll
    for (int i = 0; i < 4; ++i) *(us8*)&As[awoff[i]] = aReg[i];
#pragma unroll
    for (int i = 0; i < 4; ++i) {
      float4 v = bReg[i];
      uint2 o; o.x = cvt_pk_bf16(v.x, v.y); o.y = cvt_pk_bf16(v.z, v.w);
      *(uint2*)&Bs[bwoff[i]] = o;
    }
    __syncthreads();
    if (ks + 1 < H_DIM / BK) { loadA((ks + 1) * BK); loadB((ks + 1) * BK); }
#pragma unroll
    for (int kk = 0; kk < 2; ++kk) {
      int k0 = kk * 32 + lk8;
      bf16x8 a[4], bb[2];
#pragma unroll
      for (int mr = 0; mr < 4; ++mr) {
        int r = wm * 64 + mr * 16 + lr;
        a[mr] = *(const bf16x8*)&As[r * BK + (k0 ^ ((r & 7) << 3))];
      }
#pragma unroll
      for (int nr = 0; nr < 2; ++nr) {
        int r = (wn * 2 + nr) * 16 + lr;
        bb[nr] = *(const bf16x8*)&Bs[r * BK + (k0 ^ ((r & 7) << 3))];
      }
#pragma unroll
      for (int mr = 0; mr < 4; ++mr)
#pragma unroll
        for (int nr = 0; nr < 2; ++nr)
          acc[mr][nr] = __builtin_amdgcn_mfma_f32_16x16x32_bf16(a[mr], bb[nr], acc[mr][nr], 0, 0, 0);
    }
  }

  // SwiGLU: acc[mr][0]=gate frag, acc[mr][1]=up frag, col = n0 + wn*16 + lr
#pragma unroll
  for (int mr = 0; mr < 4; ++mr) {
    f32x4 g = acc[mr][0], u = acc[mr][1];
    int ncol = n0 + wn * 16 + lr;
#pragma unroll
    for (int q = 0; q < 4; ++q) {
      int rl = wm * 64 + mr * 16 + (lane >> 4) * 4 + q;
      if (m0 + rl < cnt) {
        float gv = g[q];
        float av = gv / (1.0f + expf(-gv)) * u[q];
        act[(size_t)(off + m0 + rl) * I_DIM + ncol] = f2bf(av);
      }
    }
  }
}

// ---------------- grouped GEMM2, split-K x4 -> 4 partial fp32 buffers ----------------
// tile 64 tokens x 64 H-cols, K-chunk 1024 (16 steps).
// grid 8192: b=((pl*16+mt)<<3)|x, panel=pl*8+x in [0,512): e=panel>>6, nt=(panel&63)>>2, kc=panel&3.
__global__ __launch_bounds__(256)
void k_gemm2(const float* __restrict__ w2, const unsigned short* __restrict__ act,
             const int* __restrict__ counts, const float* __restrict__ row_w,
             float* __restrict__ yp) {
  int b = blockIdx.x;
  int x = b & 7, s = b >> 3;
  int mt = s & 15, pl = s >> 4;         // pl in [0,64)
  int panel = pl * 8 + x;               // [0,512)
  int e = panel >> 6;
  int nt = (panel & 63) >> 2, kc = panel & 3;
  int cnt = counts[e];
  int m0 = mt * 64;
  if (m0 >= cnt) return;
  int off = 0;
#pragma unroll
  for (int i = 0; i < NE; ++i) if (i < e) off += counts[i];
  int n0 = nt * 64;
  int kbase = kc * 1024;

  __shared__ __align__(16) short As[64 * BK];  // 8 KB
  __shared__ __align__(16) short Bs[64 * BK];  // 8 KB

  int tid = threadIdx.x;
  int lane = tid & 63, wid = tid >> 6;
  int wm = wid & 1, wn = wid >> 1;
  int lr = lane & 15, lk8 = (lane >> 4) * 8;

  const float* w2e = w2 + (size_t)e * H_DIM * I_DIM;
  const unsigned short* ab = act + (size_t)(off + m0) * I_DIM;

  int arow0 = tid >> 3, ack = tid & 7;   // A: 2 chunks, rows arow0+i*32
  int brow0 = tid >> 4, bck = tid & 15;  // B: 4 chunks, rows brow0+i*16

  const unsigned short* aptr[2];
  int awoff[2];
#pragma unroll
  for (int i = 0; i < 2; ++i) {
    int r = arow0 + i * 32;
    aptr[i] = ab + (size_t)r * I_DIM + kbase + ack * 8;
    awoff[i] = r * BK + ((ack * 8) ^ ((r & 7) << 3));
  }
  const float* bptr[4];
  int bwoff[4];
#pragma unroll
  for (int i = 0; i < 4; ++i) {
    int r = brow0 + i * 16;
    bptr[i] = w2e + (size_t)(n0 + r) * I_DIM + kbase + bck * 4;
    bwoff[i] = r * BK + ((bck * 4) ^ ((r & 7) << 3));
  }

  f32x4 acc[2][2];
#pragma unroll
  for (int i = 0; i < 2; ++i)
#pragma unroll
    for (int j = 0; j < 2; ++j) acc[i][j] = (f32x4){0.f, 0.f, 0.f, 0.f};

  us8 aReg[2];
  float4 bReg[4];

  auto loadA = [&](int k0) {
#pragma unroll
    for (int i = 0; i < 2; ++i) {
      us8 z = {0, 0, 0, 0, 0, 0, 0, 0};
      aReg[i] = (m0 + arow0 + i * 32 < cnt) ? *(const us8*)(aptr[i] + k0) : z;
    }
  };
  auto loadB = [&](int k0) {
#pragma unroll
    for (int i = 0; i < 4; ++i) bReg[i] = *(const float4*)(bptr[i] + k0);
  };

  loadA(0); loadB(0);

  for (int ks = 0; ks < 1024 / BK; ++ks) {
    __syncthreads();
#pragma unroll
    for (int i = 0; i < 2; ++i) *(us8*)&As[awoff[i]] = aReg[i];
#pragma unroll
    for (int i = 0; i < 4; ++i) {
      float4 v = bReg[i];
      uint2 o; o.x = cvt_pk_bf16(v.x, v.y); o.y = cvt_pk_bf16(v.z, v.w);
      *(uint2*)&Bs[bwoff[i]] = o;
    }
    __syncthreads();
    if (ks + 1 < 1024 / BK) { loadA((ks + 1) * BK); loadB((ks + 1) * BK); }
#pragma unroll
    for (int kk = 0; kk < 2; ++kk) {
      int k0 = kk * 32 + lk8;
      bf16x8 a[2], bb[2];
#pragma unroll
      for (int mr = 0; mr < 2; ++mr) {
        int r = wm * 32 + mr * 16 + lr;
        a[mr] = *(const bf16x8*)&As[r * BK + (k0 ^ ((r & 7) << 3))];
      }
#pragma unroll
      for (int nr = 0; nr < 2; ++nr) {
        int r = wn * 32 + nr * 16 + lr;
        bb[nr] = *(const bf16x8*)&Bs[r * BK + (k0 ^ ((r & 7) << 3))];
      }
#pragma unroll
      for (int mr = 0; mr < 2; ++mr)
#pragma unroll
        for (int nr = 0; nr < 2; ++nr)
          acc[mr][nr] = __builtin_amdgcn_mfma_f32_16x16x32_bf16(a[mr], bb[nr], acc[mr][nr], 0, 0, 0);
    }
  }

  float* ypc = yp + (size_t)kc * (2048 * H_DIM);
#pragma unroll
  for (int mr = 0; mr < 2; ++mr) {
#pragma unroll
    for (int q = 0; q < 4; ++q) {
      int rl = wm * 32 + mr * 16 + (lane >> 4) * 4 + q;
      if (m0 + rl >= cnt) continue;
      int grow = off + m0 + rl;
      float wgt = row_w[grow];
      float* yrow = ypc + (size_t)grow * H_DIM;
#pragma unroll
      for (int nr = 0; nr < 2; ++nr) {
        int ncol = n0 + wn * 32 + nr * 16 + lr;
        yrow[ncol] = acc[mr][nr][q] * wgt;
      }
    }
  }
}

// ---------------- combine: out[t] = sum over 2 copies x 4 K-chunks ----------------
__global__ void k_combine(const float* __restrict__ yp, const int* __restrict__ inv_row,
                          float* __restrict__ out) {
  int t = blockIdx.x, i = threadIdx.x;
  int r0 = inv_row[2 * t], r1 = inv_row[2 * t + 1];
  float4 s = make_float4(0.f, 0.f, 0.f, 0.f);
#pragma unroll
  for (int kc = 0; kc < 4; ++kc) {
    const float4* a = (const float4*)(yp + (size_t)kc * (2048 * H_DIM) + (size_t)r0 * H_DIM);
    const float4* b = (const float4*)(yp + (size_t)kc * (2048 * H_DIM) + (size_t)r1 * H_DIM);
    float4 va = a[i], vb = b[i];
    s.x += va.x + vb.x; s.y += va.y + vb.y; s.z += va.z + vb.z; s.w += va.w + vb.w;
  }
  ((float4*)(out + (size_t)t * H_DIM))[i] = s;
}

extern "C" void kernel_launch(void* const* d_in, const int* in_sizes, int n_in,
                              void* d_out, int out_size, void* d_ws, size_t ws_size,
                              hipStream_t stream) {
  const float* hs = (const float*)d_in[0];
  const float* w1 = (const float*)d_in[1];
  const float* w2 = (const float*)d_in[2];
  const float* gates = (const float*)d_in[3];
  float* out = (float*)d_out;

  char* ws = (char*)d_ws;
  int* counts = (int*)ws;                                // 32 B
  int* tok_idx = (int*)(ws + 4096);                      // 32 KB
  float* tok_w = (float*)(ws + 4096 + 32768);            // 32 KB
  int* tok_cpy = (int*)(ws + 4096 + 65536);              // 32 KB
  float* row_w = (float*)(ws + 4096 + 98304);            // 8 KB
  int* inv_row = (int*)(ws + 4096 + 98304 + 8192);       // 8 KB
  unsigned short* xpack = (unsigned short*)(ws + (1 << 17));   // 4 MB
  unsigned short* act = (unsigned short*)(ws + (8u << 20));    // 16 MB
  float* yp = (float*)(ws + (32u << 20));                      // 4 x 8 MB

  hipMemsetAsync(counts, 0, NE * sizeof(int), stream);
  k_route<<<dim3(4), dim3(256), 0, stream>>>(gates, counts, tok_idx, tok_w, tok_cpy);
  k_pack<<<dim3(NE * T_TOK), dim3(256), 0, stream>>>(hs, counts, tok_idx, tok_w, tok_cpy,
                                                     xpack, row_w, inv_row);
  k_gemm1<<<dim3(8192), dim3(256), 0, stream>>>(w1, xpack, counts, act);
  k_gemm2<<<dim3(8192), dim3(256), 0, stream>>>(w2, act, counts, row_w, yp);
  k_combine<<<dim3(T_TOK), dim3(256), 0, stream>>>(yp, inv_row, out);
}